// Round 7
// baseline (508.435 us; speedup 1.0000x reference)
//
#include <hip/hip_runtime.h>
#include <hip/hip_bf16.h>
#include <math.h>

// Problem constants
#define N1R 65536   // B*N1 query rows
#define N2R 16384   // B*N2 point rows
#define NPB 4096    // N2 per batch
#define CC  256     // COUT
#define SPLIT 4     // KNN point-dim split (occupancy)
#define SPTS (NPB / SPLIT)   // 1024 points per split
#define ASTRIDE 40  // LDS A-tile row stride in bf16 elems (80B: 16B-aligned, ~2-way banks)

typedef __attribute__((ext_vector_type(4))) float v4f;
typedef __attribute__((ext_vector_type(8))) short v8s;

static __device__ __forceinline__ short f2bs(float f) {
    union { __hip_bfloat16 h; short s; } u;
    u.h = __float2bfloat16(f);
    return u.s;
}

// ---------------------------------------------------------------------------
// W transpose + bf16 convert: WT[n][k] = bf16(W[k][n]).  W: Kd x 256.
// ---------------------------------------------------------------------------
__global__ __launch_bounds__(256)
void wtrans_kernel(const float* __restrict__ W, short* __restrict__ WT, int Kd)
{
    const int i = blockIdx.x * 256 + threadIdx.x;   // over Kd*256
    const int k = i >> 8;
    const int n = i & 255;
    WT[(size_t)n * Kd + k] = f2bs(W[i]);
}

// ---------------------------------------------------------------------------
// Point augmentation: paug[i] = {x, y, z, (x*x+y*y)+z*z}  (exact fp32, no FMA
// — must bit-match the numpy reference's pp computation).
// ---------------------------------------------------------------------------
__global__ __launch_bounds__(256)
void paug_kernel(const float* __restrict__ p2, float4* __restrict__ paug)
{
#pragma clang fp contract(off)
    const int i = blockIdx.x * 256 + threadIdx.x;   // over N2R
    const float x = p2[(size_t)i * 3 + 0];
    const float y = p2[(size_t)i * 3 + 1];
    const float z = p2[(size_t)i * 3 + 2];
    float4 v;
    v.x = x; v.y = y; v.z = z;
    v.w = (x * x + y * y) + z * z;
    paug[i] = v;
}

// ---------------------------------------------------------------------------
// Tiled GEMM: Y = X(rows x Kdim, fp32) @ W(Kdim x 256) + bias, fp32 out.
// 256 thr / 4 waves per 128x128 tile; wave -> 64x64 quadrant (4x4 MFMA grid).
// Software-pipelined: next A-chunk global loads issued during current MFMA.
// B loads issued BEFORE the A-prefetch so MFMA waits at vmcnt(4), not 0.
// ---------------------------------------------------------------------------
__global__ __launch_bounds__(256)
void gemm_tile_kernel(const float* __restrict__ X,
                      const short* __restrict__ WT,
                      const float* __restrict__ bias,
                      float* __restrict__ Y,
                      int Kdim)
{
    __shared__ short As[128 * ASTRIDE];

    const int bm0 = blockIdx.x * 128;
    const int bn0 = blockIdx.y * 128;
    const int wave = threadIdx.x >> 6;
    const int lane = threadIdx.x & 63;
    const int wm0 = (wave >> 1) * 64;
    const int wn0 = (wave & 1) * 64;
    const int col = lane & 15, quad = lane >> 4;

    const int srow = threadIdx.x >> 1;
    const int skh  = (threadIdx.x & 1) * 16;
    const float* sbase = X + (size_t)(bm0 + srow) * Kdim + skh;
    short* sdst = As + srow * ASTRIDE + skh;

    v4f acc[4][4];
#pragma unroll
    for (int i = 0; i < 4; ++i)
#pragma unroll
        for (int j = 0; j < 4; ++j) acc[i][j] = (v4f){0.f, 0.f, 0.f, 0.f};

    const short* wbase = WT + (size_t)(bn0 + wn0 + col) * Kdim + quad * 8;

    // prologue A prefetch
    v4f f0 = *(const v4f*)(sbase);
    v4f f1 = *(const v4f*)(sbase + 4);
    v4f f2v = *(const v4f*)(sbase + 8);
    v4f f3 = *(const v4f*)(sbase + 12);

    for (int k0 = 0; k0 < Kdim; k0 += 32) {
        v8s lo, hi;
#pragma unroll
        for (int j = 0; j < 4; ++j) {
            lo[j] = f2bs(f0[j]); lo[j + 4] = f2bs(f1[j]);
            hi[j] = f2bs(f2v[j]); hi[j + 4] = f2bs(f3[j]);
        }
        __syncthreads();   // previous iteration's LDS reads complete
        *(v8s*)sdst = lo;
        *(v8s*)(sdst + 8) = hi;
        __syncthreads();

        // B fragments for this k (issued first -> waited at vmcnt(4))
        v8s bf[4];
#pragma unroll
        for (int ni = 0; ni < 4; ++ni)
            bf[ni] = *(const v8s*)(wbase + (size_t)(ni * 16) * Kdim + k0);

        // A-chunk prefetch for next iteration (stays in flight through MFMA)
        if (k0 + 32 < Kdim) {
            const float* np = sbase + k0 + 32;
            f0 = *(const v4f*)np;
            f1 = *(const v4f*)(np + 4);
            f2v = *(const v4f*)(np + 8);
            f3 = *(const v4f*)(np + 12);
        }

        v8s a[4];
#pragma unroll
        for (int mi = 0; mi < 4; ++mi)
            a[mi] = *(const v8s*)(As + (wm0 + mi * 16 + col) * ASTRIDE + quad * 8);
#pragma unroll
        for (int mi = 0; mi < 4; ++mi)
#pragma unroll
            for (int ni = 0; ni < 4; ++ni)
                acc[mi][ni] = __builtin_amdgcn_mfma_f32_16x16x32_bf16(a[mi], bf[ni], acc[mi][ni], 0, 0, 0);
    }

    // epilogue: bias + store fp32
#pragma unroll
    for (int ni = 0; ni < 4; ++ni) {
        const int n = bn0 + wn0 + ni * 16 + col;
        const float bv = bias[n];
#pragma unroll
        for (int mi = 0; mi < 4; ++mi) {
            const int m = bm0 + wm0 + mi * 16 + quad * 4;
#pragma unroll
            for (int r = 0; r < 4; ++r)
                Y[(size_t)(m + r) * CC + n] = acc[mi][ni][r] + bv;
        }
    }
}

// ---------------------------------------------------------------------------
// Column stats over 256 rows per block, float4-vectorized + LDS reduce.
// ---------------------------------------------------------------------------
__global__ __launch_bounds__(256)
void stat_accum_kernel(const float* __restrict__ Y,
                       float* __restrict__ sum, float* __restrict__ sumsq)
{
    __shared__ v4f rs[256], rq[256];
    const int cg = threadIdx.x & 63;     // column group (4 cols)
    const int rw = threadIdx.x >> 6;     // row phase 0..3
    const int r0 = blockIdx.x * 256;

    v4f s = {0.f, 0.f, 0.f, 0.f}, q = {0.f, 0.f, 0.f, 0.f};
    for (int r = r0 + rw; r < r0 + 256; r += 4) {
        v4f v = *(const v4f*)(Y + (size_t)r * CC + cg * 4);
        s += v;
        q += v * v;
    }
    rs[threadIdx.x] = s;
    rq[threadIdx.x] = q;
    __syncthreads();
    if (threadIdx.x < 64) {
        const int c = threadIdx.x;
        v4f ts = rs[c] + rs[64 + c] + rs[128 + c] + rs[192 + c];
        v4f tq = rq[c] + rq[64 + c] + rq[128 + c] + rq[192 + c];
#pragma unroll
        for (int j = 0; j < 4; ++j) {
            atomicAdd(&sum[c * 4 + j], ts[j]);
            atomicAdd(&sumsq[c * 4 + j], tq[j]);
        }
    }
}

// ---------------------------------------------------------------------------
// Finalize BN constants: a = g*rsqrt(var+eps), c = beta - a*mu
// ---------------------------------------------------------------------------
__global__ __launch_bounds__(512)
void finalize_kernel(const float* __restrict__ sums,
                     const float* __restrict__ g1, const float* __restrict__ be1,
                     const float* __restrict__ g2, const float* __restrict__ be2,
                     float* __restrict__ ac)
{
    const int t = threadIdx.x;           // 0..511
    const int c = t & 255;
    const int which = t >> 8;            // 0: BN1, 1: BN2
    const float* s = sums + which * 512;
    const double n = which ? (double)N2R : (double)N1R;
    const double mu = (double)s[c] / n;
    const double var = (double)s[c + 256] / n - mu * mu;
    const float g  = which ? g2[c]  : g1[c];
    const float be = which ? be2[c] : be1[c];
    const double a  = (double)g / sqrt(var + 1e-5);
    const double cv = (double)be - a * mu;
    ac[which * 512 + c]       = (float)a;
    ac[which * 512 + 256 + c] = (float)cv;
}

// ---------------------------------------------------------------------------
// In-place BN + ReLU for f2 (Y2 buffer), float4.
// ---------------------------------------------------------------------------
__global__ __launch_bounds__(256)
void bnrelu_kernel(float* __restrict__ Y, const float* __restrict__ ac)
{
    const int i = blockIdx.x * 256 + threadIdx.x;   // over N2R*CC/4
    const int c0 = (i & 63) * 4;
    v4f a4 = *(const v4f*)(ac + c0);
    v4f c4 = *(const v4f*)(ac + 256 + c0);
    v4f v = *(v4f*)(Y + (size_t)i * 4);
#pragma unroll
    for (int j = 0; j < 4; ++j)
        v[j] = fmaxf(fmaf(a4[j], v[j], c4[j]), 0.f);
    *(v4f*)(Y + (size_t)i * 4) = v;
}

// ---------------------------------------------------------------------------
// KNN partial: 2 queries per thread, top-3 over one split of 1024 points.
// Points come from paug via wave-uniform loads (scalar path, no LDS).
// fp32 arithmetic bit-matches numpy (dot = FMA chain, d stepwise, pp from
// paug computed with the reference rounding). Strict '<' ascending scan.
// ---------------------------------------------------------------------------
__global__ __launch_bounds__(256)
void knn_partial_kernel(const float* __restrict__ p1,
                        const float4* __restrict__ paug,
                        float* __restrict__ pd, int* __restrict__ pi)
{
#pragma clang fp contract(off)
    const int qA = blockIdx.x * 512 + threadIdx.x;
    const int qB = qA + 256;
    const int s = blockIdx.y;
    const int b = qA >> 14;          // 512-aligned block => same batch for A,B
    const int base = s * SPTS;

    const float qxA = p1[(size_t)qA * 3 + 0];
    const float qyA = p1[(size_t)qA * 3 + 1];
    const float qzA = p1[(size_t)qA * 3 + 2];
    const float qqA = (qxA * qxA + qyA * qyA) + qzA * qzA;
    const float qxB = p1[(size_t)qB * 3 + 0];
    const float qyB = p1[(size_t)qB * 3 + 1];
    const float qzB = p1[(size_t)qB * 3 + 2];
    const float qqB = (qxB * qxB + qyB * qyB) + qzB * qzB;

    float b0A = 3.0e38f, b1A = 3.0e38f, b2A = 3.0e38f;
    int i0A = 0, i1A = 0, i2A = 0;
    float b0B = 3.0e38f, b1B = 3.0e38f, b2B = 3.0e38f;
    int i0B = 0, i1B = 0, i2B = 0;

    const float4* pa = paug + (size_t)b * NPB + base;

#pragma unroll 4
    for (int j = 0; j < SPTS; ++j) {
        const float4 P = pa[j];      // wave-uniform -> scalar load path
        const float dotA = fmaf(qzA, P.z, fmaf(qyA, P.y, qxA * P.x));
        const float dA = fmaf(-2.0f, dotA, qqA + P.w);
        const float dotB = fmaf(qzB, P.z, fmaf(qyB, P.y, qxB * P.x));
        const float dB = fmaf(-2.0f, dotB, qqB + P.w);
        const int jj = base + j;
        if (__ballot(dA < b2A)) {
            const bool lt2 = dA < b2A, lt1 = dA < b1A, lt0 = dA < b0A;
            b2A = lt1 ? b1A : (lt2 ? dA : b2A);  i2A = lt1 ? i1A : (lt2 ? jj : i2A);
            b1A = lt0 ? b0A : (lt1 ? dA : b1A);  i1A = lt0 ? i0A : (lt1 ? jj : i1A);
            b0A = lt0 ? dA  : b0A;               i0A = lt0 ? jj : i0A;
        }
        if (__ballot(dB < b2B)) {
            const bool lt2 = dB < b2B, lt1 = dB < b1B, lt0 = dB < b0B;
            b2B = lt1 ? b1B : (lt2 ? dB : b2B);  i2B = lt1 ? i1B : (lt2 ? jj : i2B);
            b1B = lt0 ? b0B : (lt1 ? dB : b1B);  i1B = lt0 ? i0B : (lt1 ? jj : i1B);
            b0B = lt0 ? dB  : b0B;               i0B = lt0 ? jj : i0B;
        }
    }

    const size_t oA = (size_t)qA * (SPLIT * 3) + s * 3;
    pd[oA + 0] = b0A; pd[oA + 1] = b1A; pd[oA + 2] = b2A;
    pi[oA + 0] = i0A; pi[oA + 1] = i1A; pi[oA + 2] = i2A;
    const size_t oB = (size_t)qB * (SPLIT * 3) + s * 3;
    pd[oB + 0] = b0B; pd[oB + 1] = b1B; pd[oB + 2] = b2B;
    pi[oB + 0] = i0B; pi[oB + 1] = i1B; pi[oB + 2] = i2B;
}

// ---------------------------------------------------------------------------
// KNN merge: lexicographic-(d, idx) top-3 over the 12 split candidates.
// ---------------------------------------------------------------------------
__global__ __launch_bounds__(256)
void knn_merge_kernel(const float* __restrict__ pd, const int* __restrict__ pi,
                      int* __restrict__ idx_out, float* __restrict__ w_out)
{
    const int q = blockIdx.x * 256 + threadIdx.x;
    const size_t o = (size_t)q * (SPLIT * 3);

    float b0 = 3.0e38f, b1 = 3.0e38f, b2 = 3.0e38f;
    int i0 = 0x7fffffff, i1 = 0x7fffffff, i2 = 0x7fffffff;

#pragma unroll
    for (int t = 0; t < SPLIT * 3; ++t) {
        const float d = pd[o + t];
        const int jj = pi[o + t];
        const bool lt2 = (d < b2) || (d == b2 && jj < i2);
        const bool lt1 = (d < b1) || (d == b1 && jj < i1);
        const bool lt0 = (d < b0) || (d == b0 && jj < i0);
        b2 = lt1 ? b1 : (lt2 ? d : b2);  i2 = lt1 ? i1 : (lt2 ? jj : i2);
        b1 = lt0 ? b0 : (lt1 ? d : b1);  i1 = lt0 ? i0 : (lt1 ? jj : i1);
        b0 = lt0 ? d  : b0;              i0 = lt0 ? jj : i0;
    }

    const float r0 = 1.0f / (fmaxf(b0, 0.0f) + 1e-8f);
    const float r1 = 1.0f / (fmaxf(b1, 0.0f) + 1e-8f);
    const float r2 = 1.0f / (fmaxf(b2, 0.0f) + 1e-8f);
    const float rs = (r0 + r1) + r2;

    idx_out[(size_t)q * 3 + 0] = i0;
    idx_out[(size_t)q * 3 + 1] = i1;
    idx_out[(size_t)q * 3 + 2] = i2;
    w_out[(size_t)q * 3 + 0] = r0 / rs;
    w_out[(size_t)q * 3 + 1] = r1 / rs;
    w_out[(size_t)q * 3 + 2] = r2 / rs;
}

// ---------------------------------------------------------------------------
// Final: out[row][c] = relu(a1*Y1 + c1) + sum_k w_k * f2[idx_k][c], float4.
// Block of 256 handles 4 rows (64 lanes x float4 per row).
// ---------------------------------------------------------------------------
__global__ __launch_bounds__(256)
void final_kernel(float* __restrict__ Y1out,
                  const float* __restrict__ f2,
                  const float* __restrict__ ac,        // a1[256], c1[256]
                  const int* __restrict__ idx, const float* __restrict__ w)
{
    const int r = blockIdx.x * 4 + (threadIdx.x >> 6);
    const int cg = threadIdx.x & 63;
    const int b = r >> 14;

    v4f a4 = *(const v4f*)(ac + cg * 4);
    v4f c4 = *(const v4f*)(ac + 256 + cg * 4);
    v4f y = *(const v4f*)(Y1out + (size_t)r * CC + cg * 4);
    v4f s;
#pragma unroll
    for (int j = 0; j < 4; ++j)
        s[j] = fmaxf(fmaf(a4[j], y[j], c4[j]), 0.f);

    const int*   ir = idx + (size_t)r * 3;
    const float* wr = w   + (size_t)r * 3;
#pragma unroll
    for (int k = 0; k < 3; ++k) {
        const int id = ir[k];
        const float wk = wr[k];
        v4f g = *(const v4f*)(f2 + ((size_t)(b * NPB + id)) * CC + cg * 4);
#pragma unroll
        for (int j = 0; j < 4; ++j)
            s[j] = fmaf(wk, g[j], s[j]);
    }
    *(v4f*)(Y1out + (size_t)r * CC + cg * 4) = s;
}

// ---------------------------------------------------------------------------
extern "C" void kernel_launch(void* const* d_in, const int* in_sizes, int n_in,
                              void* d_out, int out_size, void* d_ws, size_t ws_size,
                              hipStream_t stream)
{
    const float* point1 = (const float*)d_in[0];
    const float* feat1  = (const float*)d_in[1];
    const float* point2 = (const float*)d_in[2];
    const float* feat2  = (const float*)d_in[3];
    const float* W1     = (const float*)d_in[4];
    const float* b1     = (const float*)d_in[5];
    const float* g1     = (const float*)d_in[6];
    const float* beta1  = (const float*)d_in[7];
    const float* W2     = (const float*)d_in[8];
    const float* b2     = (const float*)d_in[9];
    const float* g2     = (const float*)d_in[10];
    const float* beta2  = (const float*)d_in[11];

    float* Y1 = (float*)d_out;                            // 64 MB (reused as output)

    char* ws = (char*)d_ws;
    float*  Y2    = (float*)ws;                                   // 16 MB
    float*  stats = (float*)(ws + (size_t)16777216);              // 4 KB
    float*  ac    = (float*)(ws + (size_t)16781312);              // 4 KB
    int*    idxb  = (int*)  (ws + (size_t)16785408);              // 768 KB
    float*  wb    = (float*)(ws + (size_t)17571840);              // 768 KB
    float*  pd    = (float*)(ws + (size_t)18358272);              // 3 MB
    int*    pi    = (int*)  (ws + (size_t)21504000);              // 3 MB
    short*  WT1   = (short*)(ws + (size_t)24649728);              // 128 KB
    short*  WT2   = (short*)(ws + (size_t)24780800);              // 256 KB
    float4* paug  = (float4*)(ws + (size_t)25042944);             // 256 KB

    hipMemsetAsync(stats, 0, 1024 * sizeof(float), stream);

    // Tiny prep kernels
    wtrans_kernel<<<256, 256, 0, stream>>>(W1, WT1, 256);
    wtrans_kernel<<<512, 256, 0, stream>>>(W2, WT2, 512);
    paug_kernel<<<N2R / 256, 256, 0, stream>>>(point2, paug);

    // Tiled GEMMs: grid = (rows/128, 256/128)
    gemm_tile_kernel<<<dim3(N1R / 128, 2), 256, 0, stream>>>(feat1, WT1, b1, Y1, 256);
    gemm_tile_kernel<<<dim3(N2R / 128, 2), 256, 0, stream>>>(feat2, WT2, b2, Y2, 512);

    // BN stats (256 rows per block)
    stat_accum_kernel<<<N1R / 256, 256, 0, stream>>>(Y1, stats + 0,   stats + 256);
    stat_accum_kernel<<<N2R / 256, 256, 0, stream>>>(Y2, stats + 512, stats + 768);
    finalize_kernel<<<1, 512, 0, stream>>>(stats, g1, beta1, g2, beta2, ac);

    // f2 = relu(bn(Y2)) in place (float4)
    bnrelu_kernel<<<(N2R * CC / 4) / 256, 256, 0, stream>>>(Y2, ac + 512);

    // KNN: split-4 partial scans (2 queries/thread, scalar point loads) + merge
    knn_partial_kernel<<<dim3(N1R / 512, SPLIT), 256, 0, stream>>>(point1, paug, pd, pi);
    knn_merge_kernel<<<N1R / 256, 256, 0, stream>>>(pd, pi, idxb, wb);

    // out = relu(bn(Y1)) + weighted gather of f2   (in-place on d_out, float4)
    final_kernel<<<N1R / 4, 256, 0, stream>>>(Y1, Y2, ac, idxb, wb);
}

// Round 8
// 436.372 us; speedup vs baseline: 1.1651x; 1.1651x over previous
//
#include <hip/hip_runtime.h>
#include <hip/hip_bf16.h>
#include <math.h>

// Problem constants
#define N1R 65536   // B*N1 query rows
#define N2R 16384   // B*N2 point rows
#define NPB 4096    // N2 per batch
#define CC  256     // COUT
#define SPLIT 8     // KNN point-dim split
#define SPTS (NPB / SPLIT)   // 512 points per split
#define ASTRIDE 40  // LDS A-tile row stride in bf16 elems (80B: 16B-aligned, ~2-way banks)

typedef __attribute__((ext_vector_type(4))) float v4f;
typedef __attribute__((ext_vector_type(8))) short v8s;

static __device__ __forceinline__ short f2bs(float f) {
    union { __hip_bfloat16 h; short s; } u;
    u.h = __float2bfloat16(f);
    return u.s;
}

// ---------------------------------------------------------------------------
// W transpose + bf16 convert: WT[n][k] = bf16(W[k][n]).  W: Kd x 256.
// ---------------------------------------------------------------------------
__global__ __launch_bounds__(256)
void wtrans_kernel(const float* __restrict__ W, short* __restrict__ WT, int Kd)
{
    const int i = blockIdx.x * 256 + threadIdx.x;   // over Kd*256
    const int k = i >> 8;
    const int n = i & 255;
    WT[(size_t)n * Kd + k] = f2bs(W[i]);
}

// ---------------------------------------------------------------------------
// Point augmentation: paug[i] = {x, y, z, (x*x+y*y)+z*z}  (exact fp32, no FMA
// — bit-matches the numpy reference's pp computation).
// ---------------------------------------------------------------------------
__global__ __launch_bounds__(256)
void paug_kernel(const float* __restrict__ p2, float4* __restrict__ paug)
{
#pragma clang fp contract(off)
    const int i = blockIdx.x * 256 + threadIdx.x;   // over N2R
    const float x = p2[(size_t)i * 3 + 0];
    const float y = p2[(size_t)i * 3 + 1];
    const float z = p2[(size_t)i * 3 + 2];
    float4 v;
    v.x = x; v.y = y; v.z = z;
    v.w = (x * x + y * y) + z * z;
    paug[i] = v;
}

// ---------------------------------------------------------------------------
// Tiled GEMM: Y = X(rows x Kdim, fp32) @ W(Kdim x 256) + bias, fp32 out.
// 256 thr / 4 waves per 128x128 tile; wave -> 64x64 quadrant (4x4 MFMA grid).
// Software-pipelined: next A-chunk global loads issued during current MFMA.
// ---------------------------------------------------------------------------
__global__ __launch_bounds__(256)
void gemm_tile_kernel(const float* __restrict__ X,
                      const short* __restrict__ WT,
                      const float* __restrict__ bias,
                      float* __restrict__ Y,
                      int Kdim)
{
    __shared__ short As[128 * ASTRIDE];

    const int bm0 = blockIdx.x * 128;
    const int bn0 = blockIdx.y * 128;
    const int wave = threadIdx.x >> 6;
    const int lane = threadIdx.x & 63;
    const int wm0 = (wave >> 1) * 64;
    const int wn0 = (wave & 1) * 64;
    const int col = lane & 15, quad = lane >> 4;

    const int srow = threadIdx.x >> 1;
    const int skh  = (threadIdx.x & 1) * 16;
    const float* sbase = X + (size_t)(bm0 + srow) * Kdim + skh;
    short* sdst = As + srow * ASTRIDE + skh;

    v4f acc[4][4];
#pragma unroll
    for (int i = 0; i < 4; ++i)
#pragma unroll
        for (int j = 0; j < 4; ++j) acc[i][j] = (v4f){0.f, 0.f, 0.f, 0.f};

    const short* wbase = WT + (size_t)(bn0 + wn0 + col) * Kdim + quad * 8;

    // prologue A prefetch
    v4f f0 = *(const v4f*)(sbase);
    v4f f1 = *(const v4f*)(sbase + 4);
    v4f f2v = *(const v4f*)(sbase + 8);
    v4f f3 = *(const v4f*)(sbase + 12);

    for (int k0 = 0; k0 < Kdim; k0 += 32) {
        v8s lo, hi;
#pragma unroll
        for (int j = 0; j < 4; ++j) {
            lo[j] = f2bs(f0[j]); lo[j + 4] = f2bs(f1[j]);
            hi[j] = f2bs(f2v[j]); hi[j + 4] = f2bs(f3[j]);
        }
        __syncthreads();   // previous iteration's LDS reads complete
        *(v8s*)sdst = lo;
        *(v8s*)(sdst + 8) = hi;
        __syncthreads();

        // B fragments for this k (issued first -> earlier vmcnt slot)
        v8s bf[4];
#pragma unroll
        for (int ni = 0; ni < 4; ++ni)
            bf[ni] = *(const v8s*)(wbase + (size_t)(ni * 16) * Kdim + k0);

        // A-chunk prefetch for next iteration (stays in flight through MFMA)
        if (k0 + 32 < Kdim) {
            const float* np = sbase + k0 + 32;
            f0 = *(const v4f*)np;
            f1 = *(const v4f*)(np + 4);
            f2v = *(const v4f*)(np + 8);
            f3 = *(const v4f*)(np + 12);
        }

        v8s a[4];
#pragma unroll
        for (int mi = 0; mi < 4; ++mi)
            a[mi] = *(const v8s*)(As + (wm0 + mi * 16 + col) * ASTRIDE + quad * 8);
#pragma unroll
        for (int mi = 0; mi < 4; ++mi)
#pragma unroll
            for (int ni = 0; ni < 4; ++ni)
                acc[mi][ni] = __builtin_amdgcn_mfma_f32_16x16x32_bf16(a[mi], bf[ni], acc[mi][ni], 0, 0, 0);
    }

    // epilogue: bias + store fp32
#pragma unroll
    for (int ni = 0; ni < 4; ++ni) {
        const int n = bn0 + wn0 + ni * 16 + col;
        const float bv = bias[n];
#pragma unroll
        for (int mi = 0; mi < 4; ++mi) {
            const int m = bm0 + wm0 + mi * 16 + quad * 4;
#pragma unroll
            for (int r = 0; r < 4; ++r)
                Y[(size_t)(m + r) * CC + n] = acc[mi][ni][r] + bv;
        }
    }
}

// ---------------------------------------------------------------------------
// Column stats over 256 rows per block, float4-vectorized + LDS reduce.
// ---------------------------------------------------------------------------
__global__ __launch_bounds__(256)
void stat_accum_kernel(const float* __restrict__ Y,
                       float* __restrict__ sum, float* __restrict__ sumsq)
{
    __shared__ v4f rs[256], rq[256];
    const int cg = threadIdx.x & 63;     // column group (4 cols)
    const int rw = threadIdx.x >> 6;     // row phase 0..3
    const int r0 = blockIdx.x * 256;

    v4f s = {0.f, 0.f, 0.f, 0.f}, q = {0.f, 0.f, 0.f, 0.f};
    for (int r = r0 + rw; r < r0 + 256; r += 4) {
        v4f v = *(const v4f*)(Y + (size_t)r * CC + cg * 4);
        s += v;
        q += v * v;
    }
    rs[threadIdx.x] = s;
    rq[threadIdx.x] = q;
    __syncthreads();
    if (threadIdx.x < 64) {
        const int c = threadIdx.x;
        v4f ts = rs[c] + rs[64 + c] + rs[128 + c] + rs[192 + c];
        v4f tq = rq[c] + rq[64 + c] + rq[128 + c] + rq[192 + c];
#pragma unroll
        for (int j = 0; j < 4; ++j) {
            atomicAdd(&sum[c * 4 + j], ts[j]);
            atomicAdd(&sumsq[c * 4 + j], tq[j]);
        }
    }
}

// ---------------------------------------------------------------------------
// Finalize BN constants: a = g*rsqrt(var+eps), c = beta - a*mu
// ---------------------------------------------------------------------------
__global__ __launch_bounds__(512)
void finalize_kernel(const float* __restrict__ sums,
                     const float* __restrict__ g1, const float* __restrict__ be1,
                     const float* __restrict__ g2, const float* __restrict__ be2,
                     float* __restrict__ ac)
{
    const int t = threadIdx.x;           // 0..511
    const int c = t & 255;
    const int which = t >> 8;            // 0: BN1, 1: BN2
    const float* s = sums + which * 512;
    const double n = which ? (double)N2R : (double)N1R;
    const double mu = (double)s[c] / n;
    const double var = (double)s[c + 256] / n - mu * mu;
    const float g  = which ? g2[c]  : g1[c];
    const float be = which ? be2[c] : be1[c];
    const double a  = (double)g / sqrt(var + 1e-5);
    const double cv = (double)be - a * mu;
    ac[which * 512 + c]       = (float)a;
    ac[which * 512 + 256 + c] = (float)cv;
}

// ---------------------------------------------------------------------------
// In-place BN + ReLU for f2 (Y2 buffer), float4.
// ---------------------------------------------------------------------------
__global__ __launch_bounds__(256)
void bnrelu_kernel(float* __restrict__ Y, const float* __restrict__ ac)
{
    const int i = blockIdx.x * 256 + threadIdx.x;   // over N2R*CC/4
    const int c0 = (i & 63) * 4;
    v4f a4 = *(const v4f*)(ac + c0);
    v4f c4 = *(const v4f*)(ac + 256 + c0);
    v4f v = *(v4f*)(Y + (size_t)i * 4);
#pragma unroll
    for (int j = 0; j < 4; ++j)
        v[j] = fmaxf(fmaf(a4[j], v[j], c4[j]), 0.f);
    *(v4f*)(Y + (size_t)i * 4) = v;
}

// ---------------------------------------------------------------------------
// KNN partial: 2 queries/thread, top-3 over one split of 512 points.
// Points staged to LDS (uniform ds_read_b128 broadcast, conflict-free);
// one read serves both queries. Wave count stays 4096 (16/CU, 4/SIMD).
// fp32 arithmetic bit-matches numpy:
//   qq/pp: products pre-rounded, sequential adds, no FMA (contract off)
//   dot  : fma(z,pz, fma(y,py, x*px))  == einsum inner FMA chain
//   d    : fmaf(-2, dot, qq+pp)        == (qq+pp) - 2*dot (2*dot exact)
// Strict '<' ascending scan; cross-split ties resolved in merge.
// ---------------------------------------------------------------------------
__global__ __launch_bounds__(256)
void knn_partial_kernel(const float* __restrict__ p1,
                        const float4* __restrict__ paug,
                        float* __restrict__ pd, int* __restrict__ pi)
{
#pragma clang fp contract(off)
    __shared__ float4 sp[SPTS];

    const int qA = blockIdx.x * 512 + threadIdx.x;
    const int qB = qA + 256;
    const int s = blockIdx.y;
    const int b = qA >> 14;          // 512-aligned block => same batch for A,B
    const int base = s * SPTS;

    const float qxA = p1[(size_t)qA * 3 + 0];
    const float qyA = p1[(size_t)qA * 3 + 1];
    const float qzA = p1[(size_t)qA * 3 + 2];
    const float qqA = (qxA * qxA + qyA * qyA) + qzA * qzA;
    const float qxB = p1[(size_t)qB * 3 + 0];
    const float qyB = p1[(size_t)qB * 3 + 1];
    const float qzB = p1[(size_t)qB * 3 + 2];
    const float qqB = (qxB * qxB + qyB * qyB) + qzB * qzB;

    // stage this split's points (pp precomputed in paug with exact rounding)
    const float4* pa = paug + (size_t)b * NPB + base;
    for (int t = threadIdx.x; t < SPTS; t += 256)
        sp[t] = pa[t];
    __syncthreads();

    float b0A = 3.0e38f, b1A = 3.0e38f, b2A = 3.0e38f;
    int i0A = 0, i1A = 0, i2A = 0;
    float b0B = 3.0e38f, b1B = 3.0e38f, b2B = 3.0e38f;
    int i0B = 0, i1B = 0, i2B = 0;

#pragma unroll 4
    for (int j = 0; j < SPTS; ++j) {
        const float4 P = sp[j];      // wave-uniform broadcast, conflict-free
        const float dotA = fmaf(qzA, P.z, fmaf(qyA, P.y, qxA * P.x));
        const float dA = fmaf(-2.0f, dotA, qqA + P.w);
        const float dotB = fmaf(qzB, P.z, fmaf(qyB, P.y, qxB * P.x));
        const float dB = fmaf(-2.0f, dotB, qqB + P.w);
        const int jj = base + j;
        if (__ballot(dA < b2A)) {
            const bool lt2 = dA < b2A, lt1 = dA < b1A, lt0 = dA < b0A;
            b2A = lt1 ? b1A : (lt2 ? dA : b2A);  i2A = lt1 ? i1A : (lt2 ? jj : i2A);
            b1A = lt0 ? b0A : (lt1 ? dA : b1A);  i1A = lt0 ? i0A : (lt1 ? jj : i1A);
            b0A = lt0 ? dA  : b0A;               i0A = lt0 ? jj : i0A;
        }
        if (__ballot(dB < b2B)) {
            const bool lt2 = dB < b2B, lt1 = dB < b1B, lt0 = dB < b0B;
            b2B = lt1 ? b1B : (lt2 ? dB : b2B);  i2B = lt1 ? i1B : (lt2 ? jj : i2B);
            b1B = lt0 ? b0B : (lt1 ? dB : b1B);  i1B = lt0 ? i0B : (lt1 ? jj : i1B);
            b0B = lt0 ? dB  : b0B;               i0B = lt0 ? jj : i0B;
        }
    }

    const size_t oA = (size_t)qA * (SPLIT * 3) + s * 3;
    pd[oA + 0] = b0A; pd[oA + 1] = b1A; pd[oA + 2] = b2A;
    pi[oA + 0] = i0A; pi[oA + 1] = i1A; pi[oA + 2] = i2A;
    const size_t oB = (size_t)qB * (SPLIT * 3) + s * 3;
    pd[oB + 0] = b0B; pd[oB + 1] = b1B; pd[oB + 2] = b2B;
    pi[oB + 0] = i0B; pi[oB + 1] = i1B; pi[oB + 2] = i2B;
}

// ---------------------------------------------------------------------------
// KNN merge: lexicographic-(d, idx) top-3 over the 24 split candidates.
// ---------------------------------------------------------------------------
__global__ __launch_bounds__(256)
void knn_merge_kernel(const float* __restrict__ pd, const int* __restrict__ pi,
                      int* __restrict__ idx_out, float* __restrict__ w_out)
{
    const int q = blockIdx.x * 256 + threadIdx.x;
    const size_t o = (size_t)q * (SPLIT * 3);

    float b0 = 3.0e38f, b1 = 3.0e38f, b2 = 3.0e38f;
    int i0 = 0x7fffffff, i1 = 0x7fffffff, i2 = 0x7fffffff;

#pragma unroll
    for (int t = 0; t < SPLIT * 3; ++t) {
        const float d = pd[o + t];
        const int jj = pi[o + t];
        const bool lt2 = (d < b2) || (d == b2 && jj < i2);
        const bool lt1 = (d < b1) || (d == b1 && jj < i1);
        const bool lt0 = (d < b0) || (d == b0 && jj < i0);
        b2 = lt1 ? b1 : (lt2 ? d : b2);  i2 = lt1 ? i1 : (lt2 ? jj : i2);
        b1 = lt0 ? b0 : (lt1 ? d : b1);  i1 = lt0 ? i0 : (lt1 ? jj : i1);
        b0 = lt0 ? d  : b0;              i0 = lt0 ? jj : i0;
    }

    const float r0 = 1.0f / (fmaxf(b0, 0.0f) + 1e-8f);
    const float r1 = 1.0f / (fmaxf(b1, 0.0f) + 1e-8f);
    const float r2 = 1.0f / (fmaxf(b2, 0.0f) + 1e-8f);
    const float rs = (r0 + r1) + r2;

    idx_out[(size_t)q * 3 + 0] = i0;
    idx_out[(size_t)q * 3 + 1] = i1;
    idx_out[(size_t)q * 3 + 2] = i2;
    w_out[(size_t)q * 3 + 0] = r0 / rs;
    w_out[(size_t)q * 3 + 1] = r1 / rs;
    w_out[(size_t)q * 3 + 2] = r2 / rs;
}

// ---------------------------------------------------------------------------
// Final: out[row][c] = relu(a1*Y1 + c1) + sum_k w_k * f2[idx_k][c], float4.
// ---------------------------------------------------------------------------
__global__ __launch_bounds__(256)
void final_kernel(float* __restrict__ Y1out,
                  const float* __restrict__ f2,
                  const float* __restrict__ ac,        // a1[256], c1[256]
                  const int* __restrict__ idx, const float* __restrict__ w)
{
    const int r = blockIdx.x * 4 + (threadIdx.x >> 6);
    const int cg = threadIdx.x & 63;
    const int b = r >> 14;

    v4f a4 = *(const v4f*)(ac + cg * 4);
    v4f c4 = *(const v4f*)(ac + 256 + cg * 4);
    v4f y = *(const v4f*)(Y1out + (size_t)r * CC + cg * 4);
    v4f s;
#pragma unroll
    for (int j = 0; j < 4; ++j)
        s[j] = fmaxf(fmaf(a4[j], y[j], c4[j]), 0.f);

    const int*   ir = idx + (size_t)r * 3;
    const float* wr = w   + (size_t)r * 3;
#pragma unroll
    for (int k = 0; k < 3; ++k) {
        const int id = ir[k];
        const float wk = wr[k];
        v4f g = *(const v4f*)(f2 + ((size_t)(b * NPB + id)) * CC + cg * 4);
#pragma unroll
        for (int j = 0; j < 4; ++j)
            s[j] = fmaf(wk, g[j], s[j]);
    }
    *(v4f*)(Y1out + (size_t)r * CC + cg * 4) = s;
}

// ---------------------------------------------------------------------------
extern "C" void kernel_launch(void* const* d_in, const int* in_sizes, int n_in,
                              void* d_out, int out_size, void* d_ws, size_t ws_size,
                              hipStream_t stream)
{
    const float* point1 = (const float*)d_in[0];
    const float* feat1  = (const float*)d_in[1];
    const float* point2 = (const float*)d_in[2];
    const float* feat2  = (const float*)d_in[3];
    const float* W1     = (const float*)d_in[4];
    const float* b1     = (const float*)d_in[5];
    const float* g1     = (const float*)d_in[6];
    const float* beta1  = (const float*)d_in[7];
    const float* W2     = (const float*)d_in[8];
    const float* b2     = (const float*)d_in[9];
    const float* g2     = (const float*)d_in[10];
    const float* beta2  = (const float*)d_in[11];

    float* Y1 = (float*)d_out;                            // 64 MB (reused as output)

    char* ws = (char*)d_ws;
    float*  Y2    = (float*)ws;                                   // 16 MB
    float*  stats = (float*)(ws + (size_t)16777216);              // 4 KB
    float*  ac    = (float*)(ws + (size_t)16781312);              // 4 KB
    int*    idxb  = (int*)  (ws + (size_t)16785408);              // 768 KB
    float*  wb    = (float*)(ws + (size_t)17571840);              // 768 KB
    float*  pd    = (float*)(ws + (size_t)18358272);              // 6 MB (24/query)
    int*    pi    = (int*)  (ws + (size_t)24649728);              // 6 MB
    short*  WT1   = (short*)(ws + (size_t)30941184);              // 128 KB
    short*  WT2   = (short*)(ws + (size_t)31072256);              // 256 KB
    float4* paug  = (float4*)(ws + (size_t)31334400);             // 256 KB

    hipMemsetAsync(stats, 0, 1024 * sizeof(float), stream);

    // Tiny prep kernels
    wtrans_kernel<<<256, 256, 0, stream>>>(W1, WT1, 256);
    wtrans_kernel<<<512, 256, 0, stream>>>(W2, WT2, 512);
    paug_kernel<<<N2R / 256, 256, 0, stream>>>(point2, paug);

    // Tiled GEMMs: grid = (rows/128, 256/128)
    gemm_tile_kernel<<<dim3(N1R / 128, 2), 256, 0, stream>>>(feat1, WT1, b1, Y1, 256);
    gemm_tile_kernel<<<dim3(N2R / 128, 2), 256, 0, stream>>>(feat2, WT2, b2, Y2, 512);

    // BN stats (256 rows per block)
    stat_accum_kernel<<<N1R / 256, 256, 0, stream>>>(Y1, stats + 0,   stats + 256);
    stat_accum_kernel<<<N2R / 256, 256, 0, stream>>>(Y2, stats + 512, stats + 768);
    finalize_kernel<<<1, 512, 0, stream>>>(stats, g1, beta1, g2, beta2, ac);

    // f2 = relu(bn(Y2)) in place (float4)
    bnrelu_kernel<<<(N2R * CC / 4) / 256, 256, 0, stream>>>(Y2, ac + 512);

    // KNN: split-8 partial scans (2 queries/thread, LDS-staged points) + merge
    knn_partial_kernel<<<dim3(N1R / 512, SPLIT), 256, 0, stream>>>(point1, paug, pd, pi);
    knn_merge_kernel<<<N1R / 256, 256, 0, stream>>>(pd, pi, idxb, wb);

    // out = relu(bn(Y1)) + weighted gather of f2   (in-place on d_out, float4)
    final_kernel<<<N1R / 4, 256, 0, stream>>>(Y1, Y2, ac, idxb, wb);
}